// Round 11
// baseline (130.649 us; speedup 1.0000x reference)
//
#include <hip/hip_runtime.h>

// StructureTensorEffect: B=4, C=3, H=W=1024, fp32.
// Round 17: fast-path occupancy. R16 (b128 taps) regressed 3.4x: the
// 16-lane x 16B pattern hit 3.9M bank conflicts (R15's 1-lane-per-col
// pattern had 0) -- reverted. Corrected per-WAVE pipe accounting: DS
// ~14us/CU, VALU ~9, HBM writes ~8; the 37.5us fast floor ~= their SUM
// (no overlap). Confound discovered: ALL fast-path comparisons R7-R14
// were masked by the ~41us border critical path; the only fast path
// measured post-border-fix is the persistent 2-block/CU one (2 waves/
// SIMD -- exactly the regime where pipes serialize). This round keeps
// R15's border tiles verbatim and swaps the fast path back to the
// VERIFIED R8/R9 single-shot tile (33KB LDS, one barrier, single-shot
// 3-channel global_load_lds staging) with __launch_bounds__(256,4) ->
// 4 blocks/CU = 16 waves/CU = 4/SIMD, 2x the wave pool, so one block's
// DS/VALU overlaps its neighbors' staging/stores. Null result (st
// ~37) would prove pipe-summing is occupancy-independent -> next lever
// is DS-count cut done right (ds_read2 pairing, same lane pattern).

#define W_ 1024
#define H_ 1024
#define PLANE (1 << 20)
#define TCOLS 64
#define TROWS 32
#define ROWS 8
#define LSTRIDE 72     // staged cols: x0-4 .. x0+67 (18 float4 groups)

#define BX_ROWS 128    // rows per x-border block
#define BX_SLOTS 134   // BX_ROWS + 6 staged rows
#define BX_CH 1072     // BX_SLOTS * 8 floats per channel
#define BX_NG 804      // 3 * BX_SLOTS * 2 float4 groups

__device__ __forceinline__ float lerp1(float a, float b, float f) {
    return fmaf(f, b - a, a);
}

// async 16B global->LDS copy (gfx950). Dest must be linear in lane order.
__device__ __forceinline__ void async_copy16(const float* g, float* s) {
    __builtin_amdgcn_global_load_lds(
        (const __attribute__((address_space(1))) unsigned int*)g,
        (__attribute__((address_space(3))) unsigned int*)s,
        16, 0, 0);
}

// Exact per-pixel reference path (any sigma, any border) — verified R1-R16.
__device__ void slow_pixel(const float* __restrict__ Xb, float* __restrict__ Ob,
                           float sg, int xi, int y)
{
    float imf = floorf(-sg), ipf = floorf(sg);
    float fm  = -sg - imf;
    float fp  =  sg - ipf;
    int   im  = (int)imf, ip = (int)ipf;

    int cm0 = min(max(xi + im, 0), W_ - 1), cm1 = min(cm0 + 1, W_ - 1);
    int cp0 = min(max(xi + ip, 0), W_ - 1), cp1 = min(cp0 + 1, W_ - 1);
    int rm0 = min(max(y + im, 0), H_ - 1),  rm1 = min(rm0 + 1, H_ - 1);
    int rp0 = min(max(y + ip, 0), H_ - 1),  rp1 = min(rp0 + 1, H_ - 1);

    int o_rm0 = rm0 << 10, o_rm1 = rm1 << 10;
    int o_rp0 = rp0 << 10, o_rp1 = rp1 << 10;
    int o_r0  = y   << 10;

    float oxx = 0.f, oyy = 0.f, oxy = 0.f;

    #pragma unroll
    for (int c = 0; c < 3; ++c) {
        const float* base = Xb + ((size_t)c << 20);

        float hm_m0 = lerp1(base[o_rm0 + cm0], base[o_rm0 + cm1], fm);
        float hm_m1 = lerp1(base[o_rm1 + cm0], base[o_rm1 + cm1], fm);
        float hm_0  = lerp1(base[o_r0  + cm0], base[o_r0  + cm1], fm);
        float hm_p0 = lerp1(base[o_rp0 + cm0], base[o_rp0 + cm1], fm);
        float hm_p1 = lerp1(base[o_rp1 + cm0], base[o_rp1 + cm1], fm);
        float hp_m0 = lerp1(base[o_rm0 + cp0], base[o_rm0 + cp1], fp);
        float hp_m1 = lerp1(base[o_rm1 + cp0], base[o_rm1 + cp1], fp);
        float hp_0  = lerp1(base[o_r0  + cp0], base[o_r0  + cp1], fp);
        float hp_p0 = lerp1(base[o_rp0 + cp0], base[o_rp0 + cp1], fp);
        float hp_p1 = lerp1(base[o_rp1 + cp0], base[o_rp1 + cp1], fp);
        float h0_m0 = base[o_rm0 + xi], h0_m1 = base[o_rm1 + xi];
        float h0_p0 = base[o_rp0 + xi], h0_p1 = base[o_rp1 + xi];

        float t0 = lerp1(hm_m0, hm_m1, fm);
        float t1 = hm_0;
        float t2 = lerp1(hm_p0, hm_p1, fp);
        float t3 = lerp1(h0_m0, h0_m1, fm);
        float t4 = lerp1(h0_p0, h0_p1, fp);
        float t5 = lerp1(hp_m0, hp_m1, fm);
        float t6 = hp_0;
        float t7 = lerp1(hp_p0, hp_p1, fp);

        float su = 0.25f * (t5 + t7 - t0 - t2) + 0.5f * (t6 - t1);
        float sv = 0.25f * (t2 + t7 - t0 - t5) + 0.5f * (t4 - t3);

        float l2 = (c == 0) ? 10000.f : 1.f;
        oxx = fmaf(l2 * su, su, oxx);
        oyy = fmaf(l2 * sv, sv, oyy);
        oxy = fmaf(l2 * su, sv, oxy);
    }

    int pix = (y << 10) | xi;
    Ob[pix]             = oxx;
    Ob[PLANE + pix]     = oyy;
    Ob[2 * PLANE + pix] = oxy;
}

// x-border tile (R15-verified): stage 8 cols x 134 clamped rows x 3 ch
// into LDS, then compute the 3 border columns exactly.
template<int IP>
__device__ void border_x_tile(const float* __restrict__ Xb, float* __restrict__ Ob,
                              float fp, float fm, int side, int y0b,
                              int tid, float* smem)
{
    const int cb = side ? (W_ - 8) : 0;
    constexpr int im = -IP - 1, ip = IP;

    #pragma unroll
    for (int it = 0; it < 3; ++it) {
        int g   = it * 256 + tid;
        int ch  = g / 268;
        int rem = g - ch * 268;
        int slot = rem >> 1, grp = rem & 1;
        int rr  = min(max(y0b - 3 + slot, 0), H_ - 1);
        async_copy16(Xb + ((size_t)ch << 20) + (rr << 10) + cb + grp * 4,
                     smem + g * 4);
    }
    {
        int g = 768 + tid;
        if (g < BX_NG) {
            int ch  = g / 268;
            int rem = g - ch * 268;
            int slot = rem >> 1, grp = rem & 1;
            int rr  = min(max(y0b - 3 + slot, 0), H_ - 1);
            async_copy16(Xb + ((size_t)ch << 20) + (rr << 10) + cb + grp * 4,
                         smem + g * 4);
        }
    }
    __syncthreads();

    #pragma unroll
    for (int it = 0; it < 2; ++it) {
        int p = it * 256 + tid;
        if (p < 3 * BX_ROWS) {
            int r   = p / 3;
            int cc_ = p - r * 3;
            int y   = y0b + r;
            int xi  = cb + (side ? 5 + cc_ : cc_);

            int cm0 = min(max(xi + im, 0), W_ - 1), cm1 = min(cm0 + 1, W_ - 1);
            int cp0 = min(max(xi + ip, 0), W_ - 1), cp1 = min(cp0 + 1, W_ - 1);
            int rm0 = min(max(y + im, 0), H_ - 1),  rm1 = min(rm0 + 1, H_ - 1);
            int rp0 = min(max(y + ip, 0), H_ - 1),  rp1 = min(rp0 + 1, H_ - 1);

            int s_m0 = (rm0 - y0b + 3) << 3, s_m1 = (rm1 - y0b + 3) << 3;
            int s_p0 = (rp0 - y0b + 3) << 3, s_p1 = (rp1 - y0b + 3) << 3;
            int s_0  = (y   - y0b + 3) << 3;
            int lm0 = cm0 - cb, lm1 = cm1 - cb;
            int lp0 = cp0 - cb, lp1 = cp1 - cb;
            int lxi = xi - cb;

            float oxx = 0.f, oyy = 0.f, oxy = 0.f;
            #pragma unroll
            for (int c = 0; c < 3; ++c) {
                const float* base = smem + c * BX_CH;

                float hm_m0 = lerp1(base[s_m0 + lm0], base[s_m0 + lm1], fm);
                float hm_m1 = lerp1(base[s_m1 + lm0], base[s_m1 + lm1], fm);
                float hm_0  = lerp1(base[s_0  + lm0], base[s_0  + lm1], fm);
                float hm_p0 = lerp1(base[s_p0 + lm0], base[s_p0 + lm1], fm);
                float hm_p1 = lerp1(base[s_p1 + lm0], base[s_p1 + lm1], fm);
                float hp_m0 = lerp1(base[s_m0 + lp0], base[s_m0 + lp1], fp);
                float hp_m1 = lerp1(base[s_m1 + lp0], base[s_m1 + lp1], fp);
                float hp_0  = lerp1(base[s_0  + lp0], base[s_0  + lp1], fp);
                float hp_p0 = lerp1(base[s_p0 + lp0], base[s_p0 + lp1], fp);
                float hp_p1 = lerp1(base[s_p1 + lp0], base[s_p1 + lp1], fp);
                float h0_m0 = base[s_m0 + lxi], h0_m1 = base[s_m1 + lxi];
                float h0_p0 = base[s_p0 + lxi], h0_p1 = base[s_p1 + lxi];

                float t0 = lerp1(hm_m0, hm_m1, fm);
                float t1 = hm_0;
                float t2 = lerp1(hm_p0, hm_p1, fp);
                float t3 = lerp1(h0_m0, h0_m1, fm);
                float t4 = lerp1(h0_p0, h0_p1, fp);
                float t5 = lerp1(hp_m0, hp_m1, fm);
                float t6 = hp_0;
                float t7 = lerp1(hp_p0, hp_p1, fp);

                float su = 0.25f * (t5 + t7 - t0 - t2) + 0.5f * (t6 - t1);
                float sv = 0.25f * (t2 + t7 - t0 - t5) + 0.5f * (t4 - t3);

                float l2 = (c == 0) ? 10000.f : 1.f;
                oxx = fmaf(l2 * su, su, oxx);
                oyy = fmaf(l2 * sv, sv, oyy);
                oxy = fmaf(l2 * su, sv, oxy);
            }

            int pix = (y << 10) | xi;
            Ob[pix]             = oxx;
            Ob[PLANE + pix]     = oyy;
            Ob[2 * PLANE + pix] = oxy;
        }
    }
}

template<int N>
__device__ __forceinline__ void acc(float (&arr)[N], int k, float val) {
    if (k >= 0 && k < N) arr[k] += val;   // k constant after unroll
}

// Fast tile (R8/R9-verified): block covers cols x0..x0+63, rows
// y0..y0+31. Stage ALL channels' clamped windows via async 16B copies,
// one barrier, then stream the accumulate from LDS for all 3 channels.
// Store mask (x>IP && x<1023-IP && y>IP) excludes clamp-wrong px; those
// are covered by the border paths.
template<int IP>
__device__ void fast_tile(const float* __restrict__ Xb, float* __restrict__ Ob,
                          float fp, float fm, int x0, int y0,
                          int tx, int ty, int tid, float* smem)
{
    constexpr int LROWS  = TROWS + 2 * IP + 2;   // staged rows per channel
    constexpr int RW     = ROWS + 2 * IP + 2;    // window rows per thread
    constexpr int NG     = 3 * LROWS * 18;       // float4 groups, all channels
    constexpr int FULLIT = NG / 256;             // guard-free iterations

    int x = x0 + tx;
    int Y = y0 + ty * ROWS;

    auto stage = [&](int g) {
        int row  = g / 18;             // 0 .. 3*LROWS-1
        int grp  = g - row * 18;
        int c    = row / LROWS;
        int lrow = row - c * LROWS;
        int gr   = min(max(y0 - IP - 1 + lrow, 0), H_ - 1);
        int gc   = min(max(x0 - 4 + grp * 4, 0), W_ - 4);
        async_copy16(Xb + ((size_t)c << 20) + (gr << 10) + gc,
                     smem + g * 4);    // LDS linear in g: lane-contiguous
    };

    #pragma unroll
    for (int it = 0; it < FULLIT; ++it)
        stage(it * 256 + tid);         // uniform exec
    if (FULLIT * 256 + tid < NG)       // single guarded tail copy
        stage(FULLIT * 256 + tid);

    __syncthreads();   // vmcnt(0) drain + barrier

    float oxx[ROWS], oyy[ROWS], oxy[ROWS];
    #pragma unroll
    for (int k = 0; k < ROWS; ++k) { oxx[k] = 0.f; oyy[k] = 0.f; oxy[k] = 0.f; }

    // thread's LDS read base: window row w of channel c lives at LDS row
    // c*LROWS + ty*ROWS + w; LDS col of global col gcol is gcol-(x0-4);
    // a0 is at col x-IP-1 -> tx + 3 - IP.
    const float* spb = smem + (ty * ROWS) * LSTRIDE + tx + (3 - IP);

    #pragma unroll
    for (int c = 0; c < 3; ++c) {
        const float* sp = spb + c * (LROWS * LSTRIDE);

        float su[ROWS], sv[ROWS];
        #pragma unroll
        for (int k = 0; k < ROWS; ++k) { su[k] = 0.f; sv[k] = 0.f; }

        #pragma unroll
        for (int w = 0; w < RW; ++w) {
            float a0 = sp[w * LSTRIDE];
            float a1 = sp[w * LSTRIDE + 1];
            float cc = sp[w * LSTRIDE + IP + 1];
            float b0 = sp[w * LSTRIDE + 2 * IP + 1];
            float b1 = sp[w * LSTRIDE + 2 * IP + 2];
            float hm = lerp1(a0, a1, fm);
            float hp = lerp1(b0, b1, fp);
            float q  = hp - hm;
            float A  = 0.25f * q;
            float hq = 0.5f  * q;
            float Bv = fmaf(0.25f, hm + hp, 0.5f * cc);
            float fpA = fp * A,  fmA = fm * A;
            float fpB = fp * Bv, fmB = fm * Bv;

            acc(su, w,              fpA);
            acc(su, w - 1,          fmA);
            acc(su, w - IP - 1,     hq);
            acc(su, w - 2*IP - 1,   fmA);
            acc(su, w - 2*IP - 2,   fpA);
            acc(sv, w,             -fpB);
            acc(sv, w - 1,         -fmB);
            acc(sv, w - 2*IP - 1,   fmB);
            acc(sv, w - 2*IP - 2,   fpB);
        }

        float l2 = (c == 0) ? 10000.f : 1.f;
        #pragma unroll
        for (int k = 0; k < ROWS; ++k) {
            oxx[k] = fmaf(l2 * su[k], su[k], oxx[k]);
            oyy[k] = fmaf(l2 * sv[k], sv[k], oyy[k]);
            oxy[k] = fmaf(l2 * su[k], sv[k], oxy[k]);
        }
    }

    bool okx = (x > IP) && (x < W_ - 1 - IP);
    #pragma unroll
    for (int k = 0; k < ROWS; ++k) {
        int y = Y + k;
        if (okx && y > IP) {
            int pix = (y << 10) | x;
            Ob[pix]             = oxx[k];
            Ob[PLANE + pix]     = oyy[k];
            Ob[2 * PLANE + pix] = oxy[k];
        }
    }
}

// block (64,4). grid = (16, 34, 4):
//   y==0: 16 x-border tiles (side = x&1, 128-row chunk = x>>1)
//   y==1: 12 y-border-row blocks (y in {0,1,2}, all x), 4 idle
//   y>=2: 32 single-tile bands
__global__ __launch_bounds__(256, 4) void st_kernel(
    const float* __restrict__ X, const float* __restrict__ S,
    float* __restrict__ O)
{
    int b  = blockIdx.z;
    const float* Xb = X + (size_t)b * 3 * PLANE;
    float*       Ob = O + (size_t)b * 3 * PLANE;
    float sg = S[b];

    int tx = threadIdx.x, ty = threadIdx.y;
    int tid = ty * 64 + tx;

    int ipv = (int)floorf(sg);
    int imv = (int)floorf(-sg);
    bool sig_ok = (imv == -ipv - 1) && ipv >= 0 && ipv <= 2;  // block-uniform
    float fp = sg - (float)ipv;
    float fm = 1.0f - fp;

    // worst case IP=2: 3ch x 38 rows x 72 cols = 32832 B -> 4 blocks/CU.
    // Border tiles reuse the first ~13 KB.
    __shared__ __align__(16) float smem[3 * (TROWS + 6) * LSTRIDE];

    if (blockIdx.y == 0) {
        int side = blockIdx.x & 1;
        int y0b  = (blockIdx.x >> 1) * BX_ROWS;
        if (sig_ok) {
            switch (ipv) {
                case 0:  border_x_tile<0>(Xb, Ob, fp, fm, side, y0b, tid, smem); break;
                case 1:  border_x_tile<1>(Xb, Ob, fp, fm, side, y0b, tid, smem); break;
                default: border_x_tile<2>(Xb, Ob, fp, fm, side, y0b, tid, smem); break;
            }
        } else {
            for (int it = 0; it < 2; ++it) {
                int p = it * 256 + tid;
                if (p < 3 * BX_ROWS) {
                    int r = p / 3, cc = p - r * 3;
                    int xi = side ? 1021 + cc : cc;
                    slow_pixel(Xb, Ob, sg, xi, y0b + r);
                }
            }
        }
        return;
    }

    if (blockIdx.y == 1) {
        // y-border rows 0..2, all x: 3072 px, 12 blocks x 256 threads.
        int p = blockIdx.x * 256 + tid;
        if (p < 3072) slow_pixel(Xb, Ob, sg, p & 1023, p >> 10);
        return;
    }

    int x0 = blockIdx.x * TCOLS;
    int y0 = (blockIdx.y - 2) * TROWS;

    if (sig_ok) {
        switch (ipv) {
            case 0:  fast_tile<0>(Xb, Ob, fp, fm, x0, y0, tx, ty, tid, smem); break;
            case 1:  fast_tile<1>(Xb, Ob, fp, fm, x0, y0, tx, ty, tid, smem); break;
            default: fast_tile<2>(Xb, Ob, fp, fm, x0, y0, tx, ty, tid, smem); break;
        }
    } else {
        for (int k = 0; k < ROWS; ++k)
            slow_pixel(Xb, Ob, sg, x0 + tx, y0 + ty * ROWS + k);
    }
}

extern "C" void kernel_launch(void* const* d_in, const int* in_sizes, int n_in,
                              void* d_out, int out_size, void* d_ws, size_t ws_size,
                              hipStream_t stream) {
    const float* x     = (const float*)d_in[0];
    const float* sigma = (const float*)d_in[1];
    float* out = (float*)d_out;

    dim3 grid(W_ / TCOLS, H_ / TROWS + 2, 4), block(64, 4);
    hipLaunchKernelGGL(st_kernel, grid, block, 0, stream, x, sigma, out);
}